// Round 6
// baseline (1955.177 us; speedup 1.0000x reference)
//
#include <hip/hip_runtime.h>

#define NB 100000
#define NG 20000
#define EL 1000000
#define EX 200000
#define NSEG (2 * NB + NG)   // concatenated CSR rows: [line->bus | g2b->bus | b2g->gen]
#define TILE 2048
#define NTILES ((NSEG + TILE - 1) / TILE)   // 108 (must be <= 256)

static __device__ __forceinline__ int uni(int x) { return __builtin_amdgcn_readfirstlane(x); }

// ---- int degree count: deg[dst[i]] += 1 ----
__global__ void counti_kernel(const int* __restrict__ dst, int* __restrict__ deg, int E) {
    int i = blockIdx.x * blockDim.x + threadIdx.x;
    if (i < E) atomicAdd(&deg[dst[i]], 1);
}

// ---- hierarchical scan, stage 1: per-tile sums (coalesced) ----
__global__ __launch_bounds__(256) void scan_part_kernel(const int* __restrict__ deg,
                                                        int* __restrict__ partial, int n) {
    __shared__ int ls[256];
    const int t = threadIdx.x;
    const int base = blockIdx.x * TILE;
    int s = 0;
    for (int i = t; i < TILE; i += 256) {
        int idx = base + i;
        s += (idx < n) ? deg[idx] : 0;
    }
    ls[t] = s;
    __syncthreads();
    for (int d = 128; d > 0; d >>= 1) {
        if (t < d) ls[t] += ls[t + d];
        __syncthreads();
    }
    if (t == 0) partial[blockIdx.x] = ls[0];
}

// ---- stage 2: single-block exclusive scan of partials; writes off[n]=total ----
__global__ __launch_bounds__(256) void scan_top_kernel(int* __restrict__ partial,
                                                       int* __restrict__ off, int nparts, int n) {
    __shared__ int ls[256];
    const int t = threadIdx.x;
    ls[t] = (t < nparts) ? partial[t] : 0;
    __syncthreads();
    for (int d = 1; d < 256; d <<= 1) {
        int x = (t >= d) ? ls[t - d] : 0;
        __syncthreads();
        ls[t] += x;
        __syncthreads();
    }
    if (t < nparts) partial[t] = (t == 0) ? 0 : ls[t - 1];
    if (t == 255) off[n] = ls[255];
}

// ---- stage 3: per-tile exclusive scan + global base; writes off and cursor ----
__global__ __launch_bounds__(256) void scan_write_kernel(const int* __restrict__ deg,
                                                         const int* __restrict__ partial,
                                                         int* __restrict__ off,
                                                         int* __restrict__ cur, int n) {
    __shared__ int ls[256];
    const int t = threadIdx.x;
    const int b0 = blockIdx.x * TILE + t * 8;
    int local[8];
    int s = 0;
#pragma unroll
    for (int j = 0; j < 8; ++j) {
        int idx = b0 + j;
        local[j] = (idx < n) ? deg[idx] : 0;
        s += local[j];
    }
    ls[t] = s;
    __syncthreads();
    for (int d = 1; d < 256; d <<= 1) {
        int x = (t >= d) ? ls[t - d] : 0;
        __syncthreads();
        ls[t] += x;
        __syncthreads();
    }
    int run = partial[blockIdx.x] + ((t == 0) ? 0 : ls[t - 1]);
#pragma unroll
    for (int j = 0; j < 8; ++j) {
        int idx = b0 + j;
        if (idx < n) { off[idx] = run; cur[idx] = run; run += local[j]; }
    }
}

// ---- CSR fill: elist[cursor[base+dst]++] = src ----
__global__ void fill_kernel(const int* __restrict__ src, const int* __restrict__ dst,
                            int* __restrict__ cursor, int* __restrict__ elist, int E, int base) {
    int i = blockIdx.x * blockDim.x + threadIdx.x;
    if (i < E) {
        int pos = atomicAdd(&cursor[base + dst[i]], 1);
        elist[pos] = src[i];
    }
}

// ---- mean over CSR segment with 4-wide load pipelining ----
static __device__ __forceinline__ float seg_mean(const float* __restrict__ h,
                                                 const int* __restrict__ elist,
                                                 int s0, int e0, int lane) {
    float s = 0.f;
    int e = s0;
    for (; e + 4 <= e0; e += 4) {
        int i0 = elist[e], i1 = elist[e + 1], i2 = elist[e + 2], i3 = elist[e + 3];
        float v0 = h[(size_t)i0 * 64 + lane];
        float v1 = h[(size_t)i1 * 64 + lane];
        float v2 = h[(size_t)i2 * 64 + lane];
        float v3 = h[(size_t)i3 * 64 + lane];
        s += v0 + v1 + v2 + v3;
    }
    for (; e < e0; ++e) s += h[(size_t)elist[e] * 64 + lane];
    return s / fmaxf((float)(e0 - s0), 1.f);
}

// ---- bus-node aggregation: Aline[b] = mean hb[src in line(b)], Ag2b[b] = mean hg[src in g2b(b)] ----
__global__ __launch_bounds__(256) void aggr_bus_kernel(
    const float* __restrict__ hb, const float* __restrict__ hg,
    const int* __restrict__ off, const int* __restrict__ elist,
    float* __restrict__ Aline, float* __restrict__ Ag2b)
{
    const int lane = threadIdx.x & 63;
    int b = uni(blockIdx.x * 4 + (threadIdx.x >> 6));
    if (b >= NB) return;
    Aline[(size_t)b * 64 + lane] = seg_mean(hb, elist, off[b], off[b + 1], lane);
    Ag2b[(size_t)b * 64 + lane]  = seg_mean(hg, elist, off[NB + b], off[NB + b + 1], lane);
}

// ---- gen-node aggregation: Ab2g[g] = mean hb[src in b2g(g)] ----
__global__ __launch_bounds__(256) void aggr_gen_kernel(
    const float* __restrict__ hb, const int* __restrict__ off, const int* __restrict__ elist,
    float* __restrict__ Ab2g)
{
    const int lane = threadIdx.x & 63;
    int g = uni(blockIdx.x * 4 + (threadIdx.x >> 6));
    if (g >= NG) return;
    Ab2g[(size_t)g * 64 + lane] = seg_mean(hb, elist, off[2 * NB + g], off[2 * NB + g + 1], lane);
}

// ---- bus combine: out = relu(h@Wsb + Al@Wl + Ag@Wg + b).
//      NO aliasing (lets uniform row loads scalarize); float4 row loads (192->48 VMEM instr/row
//      — R5 was VMEM-instruction-bound: 192 scalar loads x 4cyc = the whole 125 us);
//      grid-stride so 192 weight floats amortize over ~48 rows/wave. ----
__global__ __launch_bounds__(256, 2) void combine_bus_kernel(
    const float* __restrict__ h, const float* __restrict__ Al, const float* __restrict__ Ag,
    const float* __restrict__ Wsb, const float* __restrict__ Wl, const float* __restrict__ Wg,
    const float* __restrict__ bias, float* __restrict__ out, int n)
{
    const int lane = threadIdx.x & 63;
    const int wave = blockIdx.x * 4 + (threadIdx.x >> 6);
    const int nW = gridDim.x * 4;
    float wsb[64], wl[64], wg[64];
#pragma unroll
    for (int k = 0; k < 64; ++k) {
        wsb[k] = Wsb[k * 64 + lane];
        wl[k]  = Wl[k * 64 + lane];
        wg[k]  = Wg[k * 64 + lane];
    }
    const float bv = bias[lane];
    for (int row = uni(wave); row < n; row += nW) {
        const float4* __restrict__ hr = (const float4*)(h + (size_t)row * 64);
        const float4* __restrict__ ar = (const float4*)(Al + (size_t)row * 64);
        const float4* __restrict__ gr = (const float4*)(Ag + (size_t)row * 64);
        float a1 = 0.f, a2 = 0.f, a3 = 0.f;
#pragma unroll 4
        for (int kc = 0; kc < 16; ++kc) {
            float4 fh = hr[kc], fa = ar[kc], fg = gr[kc];
            a1 += fh.x * wsb[4 * kc] + fh.y * wsb[4 * kc + 1] + fh.z * wsb[4 * kc + 2] + fh.w * wsb[4 * kc + 3];
            a2 += fa.x * wl[4 * kc]  + fa.y * wl[4 * kc + 1]  + fa.z * wl[4 * kc + 2]  + fa.w * wl[4 * kc + 3];
            a3 += fg.x * wg[4 * kc]  + fg.y * wg[4 * kc + 1]  + fg.z * wg[4 * kc + 2]  + fg.w * wg[4 * kc + 3];
        }
        out[(size_t)row * 64 + lane] = fmaxf(a1 + a2 + a3 + bv, 0.f);
    }
}

// ---- gen combine: out = relu(h@Wsg + A@Wm + b). Same structure, no aliasing. ----
__global__ __launch_bounds__(256, 2) void combine_gen_kernel(
    const float* __restrict__ h, const float* __restrict__ A,
    const float* __restrict__ Wsg, const float* __restrict__ Wm,
    const float* __restrict__ bias, float* __restrict__ out, int n)
{
    const int lane = threadIdx.x & 63;
    const int wave = blockIdx.x * 4 + (threadIdx.x >> 6);
    const int nW = gridDim.x * 4;
    float ws[64], wm[64];
#pragma unroll
    for (int k = 0; k < 64; ++k) {
        ws[k] = Wsg[k * 64 + lane];
        wm[k] = Wm[k * 64 + lane];
    }
    const float bv = bias[lane];
    for (int row = uni(wave); row < n; row += nW) {
        const float4* __restrict__ hr = (const float4*)(h + (size_t)row * 64);
        const float4* __restrict__ ar = (const float4*)(A + (size_t)row * 64);
        float a1 = 0.f, a2 = 0.f;
#pragma unroll 4
        for (int kc = 0; kc < 16; ++kc) {
            float4 fh = hr[kc], fa = ar[kc];
            a1 += fh.x * ws[4 * kc] + fh.y * ws[4 * kc + 1] + fh.z * ws[4 * kc + 2] + fh.w * ws[4 * kc + 3];
            a2 += fa.x * wm[4 * kc] + fa.y * wm[4 * kc + 1] + fa.z * wm[4 * kc + 2] + fa.w * wm[4 * kc + 3];
        }
        out[(size_t)row * 64 + lane] = fmaxf(a1 + a2 + bv, 0.f);
    }
}

// ---- column-sum pool ----
__global__ __launch_bounds__(256) void pool_kernel(
    const float* __restrict__ h, int n, float* __restrict__ pool)
{
    int lane = threadIdx.x & 63;
    int w = threadIdx.x >> 6;
    float s = 0.f;
    for (int row = blockIdx.x * 4 + w; row < n; row += gridDim.x * 4)
        s += h[(size_t)row * 64 + lane];
    __shared__ float red[256];
    red[threadIdx.x] = s;
    __syncthreads();
    if (threadIdx.x < 64) {
        float t = red[threadIdx.x] + red[threadIdx.x + 64] + red[threadIdx.x + 128] + red[threadIdx.x + 192];
        atomicAdd(&pool[lane], t);
    }
}

// ---- head: out = relu(g @ Wh + bh) @ Wo + bo ----
__global__ void head_kernel(const float* __restrict__ pool,
                            const float* __restrict__ Wh, const float* __restrict__ bh,
                            const float* __restrict__ Wo, const float* __restrict__ bo,
                            float* __restrict__ out)
{
    __shared__ float g[128];
    __shared__ float hid[64];
    int t = threadIdx.x;  // 128 threads
    g[t] = pool[t];
    __syncthreads();
    if (t < 64) {
        float a = bh[t];
        for (int i = 0; i < 128; ++i) a += g[i] * Wh[i * 64 + t];
        hid[t] = fmaxf(a, 0.f);
    }
    __syncthreads();
    if (t < 16) {
        float a = bo[t];
        for (int j = 0; j < 64; ++j) a += hid[j] * Wo[j * 16 + t];
        out[t] = a;
    }
}

extern "C" void kernel_launch(void* const* d_in, const int* in_sizes, int n_in,
                              void* d_out, int out_size, void* d_ws, size_t ws_size,
                              hipStream_t stream)
{
    const float* x_bus   = (const float*)d_in[0];
    const float* x_gen   = (const float*)d_in[1];
    const int* line_src  = (const int*)d_in[2];
    const int* line_dst  = (const int*)d_in[3];
    const int* g2b_src   = (const int*)d_in[4];
    const int* g2b_dst   = (const int*)d_in[5];
    const int* b2g_src   = (const int*)d_in[6];
    const int* b2g_dst   = (const int*)d_in[7];
    const float* Wsb[2]  = {(const float*)d_in[8],  (const float*)d_in[15]};
    const float* Wsg[2]  = {(const float*)d_in[9],  (const float*)d_in[16]};
    const float* Wl[2]   = {(const float*)d_in[10], (const float*)d_in[17]};
    const float* Wg2b[2] = {(const float*)d_in[11], (const float*)d_in[18]};
    const float* Wb2g[2] = {(const float*)d_in[12], (const float*)d_in[19]};
    const float* bsb[2]  = {(const float*)d_in[13], (const float*)d_in[20]};
    const float* bsg[2]  = {(const float*)d_in[14], (const float*)d_in[21]};
    const float* Wh = (const float*)d_in[22];
    const float* bh = (const float*)d_in[23];
    const float* Wo = (const float*)d_in[24];
    const float* bo = (const float*)d_in[25];
    (void)in_sizes; (void)n_in; (void)out_size; (void)ws_size;

    char* wsB = (char*)d_ws;
    size_t o = 0;
    auto alloc_f = [&](size_t nelem) { float* p = (float*)(wsB + o); o += nelem * sizeof(float); return p; };
    auto alloc_i = [&](size_t nelem) { int*   p = (int*)  (wsB + o); o += nelem * sizeof(int);   return p; };

    float* H1b   = alloc_f((size_t)NB * 64);   // layer-0 bus output
    float* H1g   = alloc_f((size_t)NG * 64);   // layer-0 gen output
    float* H2b   = alloc_f((size_t)NB * 64);   // layer-1 bus output (no aliasing with combine inputs)
    float* H2g   = alloc_f((size_t)NG * 64);   // layer-1 gen output
    float* Aline = alloc_f((size_t)NB * 64);
    float* Ag2b  = alloc_f((size_t)NB * 64);
    float* Ab2g  = alloc_f((size_t)NG * 64);
    int*   elist = alloc_i(EL + 2 * EX);
    int*   deg   = alloc_i(NSEG);
    int*   off   = alloc_i(NSEG + 1);
    int*   cur   = alloc_i(NSEG);
    int*   part  = alloc_i(256);
    float* pool  = alloc_f(128);

    // ---- CSR build (graph is identical both layers; built once per call) ----
    hipMemsetAsync(deg, 0, NSEG * sizeof(int), stream);
    hipMemsetAsync(pool, 0, 128 * sizeof(float), stream);
    counti_kernel<<<(EL + 255) / 256, 256, 0, stream>>>(line_dst, deg, EL);
    counti_kernel<<<(EX + 255) / 256, 256, 0, stream>>>(g2b_dst, deg + NB, EX);
    counti_kernel<<<(EX + 255) / 256, 256, 0, stream>>>(b2g_dst, deg + 2 * NB, EX);
    scan_part_kernel<<<NTILES, 256, 0, stream>>>(deg, part, NSEG);
    scan_top_kernel<<<1, 256, 0, stream>>>(part, off, NTILES, NSEG);
    scan_write_kernel<<<NTILES, 256, 0, stream>>>(deg, part, off, cur, NSEG);
    fill_kernel<<<(EL + 255) / 256, 256, 0, stream>>>(line_src, line_dst, cur, elist, EL, 0);
    fill_kernel<<<(EX + 255) / 256, 256, 0, stream>>>(g2b_src, g2b_dst, cur, elist, EX, NB);
    fill_kernel<<<(EX + 255) / 256, 256, 0, stream>>>(b2g_src, b2g_dst, cur, elist, EX, 2 * NB);

    const int gbB = (NB + 3) / 4, gbG = (NG + 3) / 4;

    // ---- layer 0 ----
    aggr_bus_kernel<<<gbB, 256, 0, stream>>>(x_bus, x_gen, off, elist, Aline, Ag2b);
    aggr_gen_kernel<<<gbG, 256, 0, stream>>>(x_bus, off, elist, Ab2g);
    combine_bus_kernel<<<512, 256, 0, stream>>>(x_bus, Aline, Ag2b, Wsb[0], Wl[0], Wg2b[0], bsb[0], H1b, NB);
    combine_gen_kernel<<<256, 256, 0, stream>>>(x_gen, Ab2g, Wsg[0], Wb2g[0], bsg[0], H1g, NG);

    // ---- layer 1 ----
    aggr_bus_kernel<<<gbB, 256, 0, stream>>>(H1b, H1g, off, elist, Aline, Ag2b);
    aggr_gen_kernel<<<gbG, 256, 0, stream>>>(H1b, off, elist, Ab2g);
    combine_bus_kernel<<<512, 256, 0, stream>>>(H1b, Aline, Ag2b, Wsb[1], Wl[1], Wg2b[1], bsb[1], H2b, NB);
    combine_gen_kernel<<<256, 256, 0, stream>>>(H1g, Ab2g, Wsg[1], Wb2g[1], bsg[1], H2g, NG);

    // ---- pool + head ----
    pool_kernel<<<512, 256, 0, stream>>>(H2b, NB, pool);
    pool_kernel<<<512, 256, 0, stream>>>(H2g, NG, pool + 64);
    head_kernel<<<1, 128, 0, stream>>>(pool, Wh, bh, Wo, bo, (float*)d_out);
}

// Round 7
// 642.105 us; speedup vs baseline: 3.0449x; 3.0449x over previous
//
#include <hip/hip_runtime.h>

#define NB 100000
#define NG 20000
#define EL 1000000
#define EX 200000
#define NSEG (2 * NB + NG)   // concatenated CSR rows: [line->bus | g2b->bus | b2g->gen]
#define TILE 2048
#define NTILES ((NSEG + TILE - 1) / TILE)   // 108 (must be <= 256)
#define CST 65               // LDS tile stride (floats): odd -> conflict-free column reads

static __device__ __forceinline__ int uni(int x) { return __builtin_amdgcn_readfirstlane(x); }

// ---- int degree count: deg[dst[i]] += 1 ----
__global__ void counti_kernel(const int* __restrict__ dst, int* __restrict__ deg, int E) {
    int i = blockIdx.x * blockDim.x + threadIdx.x;
    if (i < E) atomicAdd(&deg[dst[i]], 1);
}

// ---- hierarchical scan, stage 1: per-tile sums (coalesced) ----
__global__ __launch_bounds__(256) void scan_part_kernel(const int* __restrict__ deg,
                                                        int* __restrict__ partial, int n) {
    __shared__ int ls[256];
    const int t = threadIdx.x;
    const int base = blockIdx.x * TILE;
    int s = 0;
    for (int i = t; i < TILE; i += 256) {
        int idx = base + i;
        s += (idx < n) ? deg[idx] : 0;
    }
    ls[t] = s;
    __syncthreads();
    for (int d = 128; d > 0; d >>= 1) {
        if (t < d) ls[t] += ls[t + d];
        __syncthreads();
    }
    if (t == 0) partial[blockIdx.x] = ls[0];
}

// ---- stage 2: single-block exclusive scan of partials; writes off[n]=total ----
__global__ __launch_bounds__(256) void scan_top_kernel(int* __restrict__ partial,
                                                       int* __restrict__ off, int nparts, int n) {
    __shared__ int ls[256];
    const int t = threadIdx.x;
    ls[t] = (t < nparts) ? partial[t] : 0;
    __syncthreads();
    for (int d = 1; d < 256; d <<= 1) {
        int x = (t >= d) ? ls[t - d] : 0;
        __syncthreads();
        ls[t] += x;
        __syncthreads();
    }
    if (t < nparts) partial[t] = (t == 0) ? 0 : ls[t - 1];
    if (t == 255) off[n] = ls[255];
}

// ---- stage 3: per-tile exclusive scan + global base; writes off and cursor ----
__global__ __launch_bounds__(256) void scan_write_kernel(const int* __restrict__ deg,
                                                         const int* __restrict__ partial,
                                                         int* __restrict__ off,
                                                         int* __restrict__ cur, int n) {
    __shared__ int ls[256];
    const int t = threadIdx.x;
    const int b0 = blockIdx.x * TILE + t * 8;
    int local[8];
    int s = 0;
#pragma unroll
    for (int j = 0; j < 8; ++j) {
        int idx = b0 + j;
        local[j] = (idx < n) ? deg[idx] : 0;
        s += local[j];
    }
    ls[t] = s;
    __syncthreads();
    for (int d = 1; d < 256; d <<= 1) {
        int x = (t >= d) ? ls[t - d] : 0;
        __syncthreads();
        ls[t] += x;
        __syncthreads();
    }
    int run = partial[blockIdx.x] + ((t == 0) ? 0 : ls[t - 1]);
#pragma unroll
    for (int j = 0; j < 8; ++j) {
        int idx = b0 + j;
        if (idx < n) { off[idx] = run; cur[idx] = run; run += local[j]; }
    }
}

// ---- CSR fill: elist[cursor[base+dst]++] = src ----
__global__ void fill_kernel(const int* __restrict__ src, const int* __restrict__ dst,
                            int* __restrict__ cursor, int* __restrict__ elist, int E, int base) {
    int i = blockIdx.x * blockDim.x + threadIdx.x;
    if (i < E) {
        int pos = atomicAdd(&cursor[base + dst[i]], 1);
        elist[pos] = src[i];
    }
}

// ---- mean over CSR segment with 4-wide load pipelining ----
static __device__ __forceinline__ float seg_mean(const float* __restrict__ h,
                                                 const int* __restrict__ elist,
                                                 int s0, int e0, int lane) {
    float s = 0.f;
    int e = s0;
    for (; e + 4 <= e0; e += 4) {
        int i0 = elist[e], i1 = elist[e + 1], i2 = elist[e + 2], i3 = elist[e + 3];
        float v0 = h[(size_t)i0 * 64 + lane];
        float v1 = h[(size_t)i1 * 64 + lane];
        float v2 = h[(size_t)i2 * 64 + lane];
        float v3 = h[(size_t)i3 * 64 + lane];
        s += v0 + v1 + v2 + v3;
    }
    for (; e < e0; ++e) s += h[(size_t)elist[e] * 64 + lane];
    return s / fmaxf((float)(e0 - s0), 1.f);
}

// ---- bus-node aggregation: Aline[b] = mean hb[src in line(b)], Ag2b[b] = mean hg[src in g2b(b)] ----
__global__ __launch_bounds__(256) void aggr_bus_kernel(
    const float* __restrict__ hb, const float* __restrict__ hg,
    const int* __restrict__ off, const int* __restrict__ elist,
    float* __restrict__ Aline, float* __restrict__ Ag2b)
{
    const int lane = threadIdx.x & 63;
    int b = uni(blockIdx.x * 4 + (threadIdx.x >> 6));
    if (b >= NB) return;
    Aline[(size_t)b * 64 + lane] = seg_mean(hb, elist, off[b], off[b + 1], lane);
    Ag2b[(size_t)b * 64 + lane]  = seg_mean(hg, elist, off[NB + b], off[NB + b + 1], lane);
}

// ---- gen-node aggregation: Ab2g[g] = mean hb[src in b2g(g)] ----
__global__ __launch_bounds__(256) void aggr_gen_kernel(
    const float* __restrict__ hb, const int* __restrict__ off, const int* __restrict__ elist,
    float* __restrict__ Ab2g)
{
    const int lane = threadIdx.x & 63;
    int g = uni(blockIdx.x * 4 + (threadIdx.x >> 6));
    if (g >= NG) return;
    Ab2g[(size_t)g * 64 + lane] = seg_mean(hb, elist, off[2 * NB + g], off[2 * NB + g + 1], lane);
}

// ---- bus combine, tiled-transposed GEMM: out = relu(h@Wsb + Al@Wl + Ag@Wg + b).
//      lane = row, 16 output cols per wave in acc[16] (robust — compiler can't drop it);
//      input tiles transposed through LDS (stride 65 = conflict-free);
//      weights as wave-uniform scalar loads (s_load, scalar pipe, L1-resident).
//      R4/R5/R6 lesson: "192 weights in per-lane VGPRs" sits on a register-allocator
//      heuristic cliff (VGPR 32/128/32 across rounds) — this structure avoids it. ----
__global__ __launch_bounds__(256) void combine_bus_kernel(
    const float* __restrict__ h, const float* __restrict__ Al, const float* __restrict__ Ag,
    const float* __restrict__ Wsb, const float* __restrict__ Wl, const float* __restrict__ Wg,
    const float* __restrict__ bias, float* __restrict__ out, int n)
{
    __shared__ float ht[64 * CST], at[64 * CST], gt[64 * CST];
    const int t = threadIdx.x;
    const int base = blockIdx.x * 64;

    // stage: coalesced float4 global reads -> transposed scalar LDS writes
#pragma unroll
    for (int i = 0; i < 4; ++i) {
        int flat = i * 1024 + t * 4;          // 0..4095
        int r = flat >> 6, c = flat & 63;
        if (base + r < n) {
            const float4 fh = *(const float4*)(h  + (size_t)(base + r) * 64 + c);
            const float4 fa = *(const float4*)(Al + (size_t)(base + r) * 64 + c);
            const float4 fg = *(const float4*)(Ag + (size_t)(base + r) * 64 + c);
            ht[(c + 0) * CST + r] = fh.x; ht[(c + 1) * CST + r] = fh.y;
            ht[(c + 2) * CST + r] = fh.z; ht[(c + 3) * CST + r] = fh.w;
            at[(c + 0) * CST + r] = fa.x; at[(c + 1) * CST + r] = fa.y;
            at[(c + 2) * CST + r] = fa.z; at[(c + 3) * CST + r] = fa.w;
            gt[(c + 0) * CST + r] = fg.x; gt[(c + 1) * CST + r] = fg.y;
            gt[(c + 2) * CST + r] = fg.z; gt[(c + 3) * CST + r] = fg.w;
        }
    }
    __syncthreads();

    const int lane = t & 63;
    const int j0 = uni((t >> 6) << 4);        // 0,16,32,48 — wave-uniform
    float acc[16];
#pragma unroll
    for (int jj = 0; jj < 16; ++jj) acc[jj] = 0.f;

    for (int k = 0; k < 64; ++k) {
        float hk = ht[k * CST + lane];
        float ak = at[k * CST + lane];
        float gk = gt[k * CST + lane];
#pragma unroll
        for (int jj = 0; jj < 16; ++jj) {
            acc[jj] += hk * Wsb[k * 64 + j0 + jj];
            acc[jj] += ak * Wl [k * 64 + j0 + jj];
            acc[jj] += gk * Wg [k * 64 + j0 + jj];
        }
    }
    __syncthreads();

    // epilogue: bias+relu, transpose back through LDS (reuse ht), coalesced store
#pragma unroll
    for (int jj = 0; jj < 16; ++jj)
        ht[(j0 + jj) * CST + lane] = fmaxf(acc[jj] + bias[j0 + jj], 0.f);
    __syncthreads();
#pragma unroll
    for (int i = 0; i < 4; ++i) {
        int flat = i * 1024 + t * 4;
        int r = flat >> 6, c = flat & 63;
        if (base + r < n) {
            float4 o4 = { ht[(c + 0) * CST + r], ht[(c + 1) * CST + r],
                          ht[(c + 2) * CST + r], ht[(c + 3) * CST + r] };
            *(float4*)(out + (size_t)(base + r) * 64 + c) = o4;
        }
    }
}

// ---- gen combine, same tiled structure, 2 input matrices: out = relu(h@Wsg + A@Wm + b) ----
__global__ __launch_bounds__(256) void combine_gen_kernel(
    const float* __restrict__ h, const float* __restrict__ A,
    const float* __restrict__ Wsg, const float* __restrict__ Wm,
    const float* __restrict__ bias, float* __restrict__ out, int n)
{
    __shared__ float ht[64 * CST], at[64 * CST];
    const int t = threadIdx.x;
    const int base = blockIdx.x * 64;
#pragma unroll
    for (int i = 0; i < 4; ++i) {
        int flat = i * 1024 + t * 4;
        int r = flat >> 6, c = flat & 63;
        if (base + r < n) {
            const float4 fh = *(const float4*)(h + (size_t)(base + r) * 64 + c);
            const float4 fa = *(const float4*)(A + (size_t)(base + r) * 64 + c);
            ht[(c + 0) * CST + r] = fh.x; ht[(c + 1) * CST + r] = fh.y;
            ht[(c + 2) * CST + r] = fh.z; ht[(c + 3) * CST + r] = fh.w;
            at[(c + 0) * CST + r] = fa.x; at[(c + 1) * CST + r] = fa.y;
            at[(c + 2) * CST + r] = fa.z; at[(c + 3) * CST + r] = fa.w;
        }
    }
    __syncthreads();
    const int lane = t & 63;
    const int j0 = uni((t >> 6) << 4);
    float acc[16];
#pragma unroll
    for (int jj = 0; jj < 16; ++jj) acc[jj] = 0.f;
    for (int k = 0; k < 64; ++k) {
        float hk = ht[k * CST + lane];
        float ak = at[k * CST + lane];
#pragma unroll
        for (int jj = 0; jj < 16; ++jj) {
            acc[jj] += hk * Wsg[k * 64 + j0 + jj];
            acc[jj] += ak * Wm [k * 64 + j0 + jj];
        }
    }
    __syncthreads();
#pragma unroll
    for (int jj = 0; jj < 16; ++jj)
        ht[(j0 + jj) * CST + lane] = fmaxf(acc[jj] + bias[j0 + jj], 0.f);
    __syncthreads();
#pragma unroll
    for (int i = 0; i < 4; ++i) {
        int flat = i * 1024 + t * 4;
        int r = flat >> 6, c = flat & 63;
        if (base + r < n) {
            float4 o4 = { ht[(c + 0) * CST + r], ht[(c + 1) * CST + r],
                          ht[(c + 2) * CST + r], ht[(c + 3) * CST + r] };
            *(float4*)(out + (size_t)(base + r) * 64 + c) = o4;
        }
    }
}

// ---- column-sum pool ----
__global__ __launch_bounds__(256) void pool_kernel(
    const float* __restrict__ h, int n, float* __restrict__ pool)
{
    int lane = threadIdx.x & 63;
    int w = threadIdx.x >> 6;
    float s = 0.f;
    for (int row = blockIdx.x * 4 + w; row < n; row += gridDim.x * 4)
        s += h[(size_t)row * 64 + lane];
    __shared__ float red[256];
    red[threadIdx.x] = s;
    __syncthreads();
    if (threadIdx.x < 64) {
        float t = red[threadIdx.x] + red[threadIdx.x + 64] + red[threadIdx.x + 128] + red[threadIdx.x + 192];
        atomicAdd(&pool[lane], t);
    }
}

// ---- head: out = relu(g @ Wh + bh) @ Wo + bo ----
__global__ void head_kernel(const float* __restrict__ pool,
                            const float* __restrict__ Wh, const float* __restrict__ bh,
                            const float* __restrict__ Wo, const float* __restrict__ bo,
                            float* __restrict__ out)
{
    __shared__ float g[128];
    __shared__ float hid[64];
    int t = threadIdx.x;  // 128 threads
    g[t] = pool[t];
    __syncthreads();
    if (t < 64) {
        float a = bh[t];
        for (int i = 0; i < 128; ++i) a += g[i] * Wh[i * 64 + t];
        hid[t] = fmaxf(a, 0.f);
    }
    __syncthreads();
    if (t < 16) {
        float a = bo[t];
        for (int j = 0; j < 64; ++j) a += hid[j] * Wo[j * 16 + t];
        out[t] = a;
    }
}

extern "C" void kernel_launch(void* const* d_in, const int* in_sizes, int n_in,
                              void* d_out, int out_size, void* d_ws, size_t ws_size,
                              hipStream_t stream)
{
    const float* x_bus   = (const float*)d_in[0];
    const float* x_gen   = (const float*)d_in[1];
    const int* line_src  = (const int*)d_in[2];
    const int* line_dst  = (const int*)d_in[3];
    const int* g2b_src   = (const int*)d_in[4];
    const int* g2b_dst   = (const int*)d_in[5];
    const int* b2g_src   = (const int*)d_in[6];
    const int* b2g_dst   = (const int*)d_in[7];
    const float* Wsb[2]  = {(const float*)d_in[8],  (const float*)d_in[15]};
    const float* Wsg[2]  = {(const float*)d_in[9],  (const float*)d_in[16]};
    const float* Wl[2]   = {(const float*)d_in[10], (const float*)d_in[17]};
    const float* Wg2b[2] = {(const float*)d_in[11], (const float*)d_in[18]};
    const float* Wb2g[2] = {(const float*)d_in[12], (const float*)d_in[19]};
    const float* bsb[2]  = {(const float*)d_in[13], (const float*)d_in[20]};
    const float* bsg[2]  = {(const float*)d_in[14], (const float*)d_in[21]};
    const float* Wh = (const float*)d_in[22];
    const float* bh = (const float*)d_in[23];
    const float* Wo = (const float*)d_in[24];
    const float* bo = (const float*)d_in[25];
    (void)in_sizes; (void)n_in; (void)out_size; (void)ws_size;

    char* wsB = (char*)d_ws;
    size_t o = 0;
    auto alloc_f = [&](size_t nelem) { float* p = (float*)(wsB + o); o += nelem * sizeof(float); return p; };
    auto alloc_i = [&](size_t nelem) { int*   p = (int*)  (wsB + o); o += nelem * sizeof(int);   return p; };

    float* H1b   = alloc_f((size_t)NB * 64);   // layer-0 bus output
    float* H1g   = alloc_f((size_t)NG * 64);   // layer-0 gen output
    float* H2b   = alloc_f((size_t)NB * 64);   // layer-1 bus output
    float* H2g   = alloc_f((size_t)NG * 64);   // layer-1 gen output
    float* Aline = alloc_f((size_t)NB * 64);
    float* Ag2b  = alloc_f((size_t)NB * 64);
    float* Ab2g  = alloc_f((size_t)NG * 64);
    int*   elist = alloc_i(EL + 2 * EX);
    int*   deg   = alloc_i(NSEG);
    int*   off   = alloc_i(NSEG + 1);
    int*   cur   = alloc_i(NSEG);
    int*   part  = alloc_i(256);
    float* pool  = alloc_f(128);

    // ---- CSR build (graph is identical both layers; built once per call) ----
    hipMemsetAsync(deg, 0, NSEG * sizeof(int), stream);
    hipMemsetAsync(pool, 0, 128 * sizeof(float), stream);
    counti_kernel<<<(EL + 255) / 256, 256, 0, stream>>>(line_dst, deg, EL);
    counti_kernel<<<(EX + 255) / 256, 256, 0, stream>>>(g2b_dst, deg + NB, EX);
    counti_kernel<<<(EX + 255) / 256, 256, 0, stream>>>(b2g_dst, deg + 2 * NB, EX);
    scan_part_kernel<<<NTILES, 256, 0, stream>>>(deg, part, NSEG);
    scan_top_kernel<<<1, 256, 0, stream>>>(part, off, NTILES, NSEG);
    scan_write_kernel<<<NTILES, 256, 0, stream>>>(deg, part, off, cur, NSEG);
    fill_kernel<<<(EL + 255) / 256, 256, 0, stream>>>(line_src, line_dst, cur, elist, EL, 0);
    fill_kernel<<<(EX + 255) / 256, 256, 0, stream>>>(g2b_src, g2b_dst, cur, elist, EX, NB);
    fill_kernel<<<(EX + 255) / 256, 256, 0, stream>>>(b2g_src, b2g_dst, cur, elist, EX, 2 * NB);

    const int gbB = (NB + 3) / 4, gbG = (NG + 3) / 4;
    const int tbB = (NB + 63) / 64, tbG = (NG + 63) / 64;

    // ---- layer 0 ----
    aggr_bus_kernel<<<gbB, 256, 0, stream>>>(x_bus, x_gen, off, elist, Aline, Ag2b);
    aggr_gen_kernel<<<gbG, 256, 0, stream>>>(x_bus, off, elist, Ab2g);
    combine_bus_kernel<<<tbB, 256, 0, stream>>>(x_bus, Aline, Ag2b, Wsb[0], Wl[0], Wg2b[0], bsb[0], H1b, NB);
    combine_gen_kernel<<<tbG, 256, 0, stream>>>(x_gen, Ab2g, Wsg[0], Wb2g[0], bsg[0], H1g, NG);

    // ---- layer 1 ----
    aggr_bus_kernel<<<gbB, 256, 0, stream>>>(H1b, H1g, off, elist, Aline, Ag2b);
    aggr_gen_kernel<<<gbG, 256, 0, stream>>>(H1b, off, elist, Ab2g);
    combine_bus_kernel<<<tbB, 256, 0, stream>>>(H1b, Aline, Ag2b, Wsb[1], Wl[1], Wg2b[1], bsb[1], H2b, NB);
    combine_gen_kernel<<<tbG, 256, 0, stream>>>(H1g, Ab2g, Wsg[1], Wb2g[1], bsg[1], H2g, NG);

    // ---- pool + head ----
    pool_kernel<<<512, 256, 0, stream>>>(H2b, NB, pool);
    pool_kernel<<<512, 256, 0, stream>>>(H2g, NG, pool + 64);
    head_kernel<<<1, 128, 0, stream>>>(pool, Wh, bh, Wo, bo, (float*)d_out);
}